// Round 3
// baseline (17566.280 us; speedup 1.0000x reference)
//
#include <hip/hip_runtime.h>

// ---------------------------------------------------------------------------
// TGCN2 forward, MI355X gfx950. ALL float tensors are fp32 (per reference);
// edge_index is int32; output fp32. bf16 is used only internally for MFMA
// (x and GRU weights pre-converted once into workspace).
// Math: H0=0 => TGCN R-gate dead, Hn=(1-Z)*H~, concat([c,0])@L == c@L_top;
// A(xW)L == (Ax)(WL) -> fold gate weights; head dots fused into producers.
// ---------------------------------------------------------------------------

typedef unsigned short u16;
typedef short s8v __attribute__((ext_vector_type(8)));
typedef float f4v __attribute__((ext_vector_type(4)));

#define NBATCH 64
#define NNODE  512
#define DCIN   128
#define DHID   256
#define NEDGE  8192

__device__ __forceinline__ u16 f2b(float f) {
    union { float f; unsigned int i; } v; v.f = f;
    unsigned int x = v.i;
    return (u16)((x + 0x7FFFu + ((x >> 16) & 1u)) >> 16);   // RNE
}
__device__ __forceinline__ float sigm(float x)  { return 1.0f / (1.0f + __expf(-x)); }
__device__ __forceinline__ float tanh_(float x) { return 1.0f - 2.0f / (1.0f + __expf(2.0f * x)); }
__device__ __forceinline__ f4v mfma16(s8v a, s8v b, f4v c) {
    return __builtin_amdgcn_mfma_f32_16x16x32_bf16(a, b, c, 0, 0, 0);
}

// ------------------------- fp32 -> bf16 conversion -------------------------
__global__ void cvt_kernel(const float* __restrict__ src, u16* __restrict__ dst, int n4) {
    int i = blockIdx.x * blockDim.x + threadIdx.x;
    if (i < n4) {
        f4v v = *(const f4v*)(src + i * 4);
        u16 o0 = f2b(v[0]), o1 = f2b(v[1]), o2 = f2b(v[2]), o3 = f2b(v[3]);
        dst[i * 4 + 0] = o0; dst[i * 4 + 1] = o1;
        dst[i * 4 + 2] = o2; dst[i * 4 + 3] = o3;
    }
}

// --------------------------- graph preprocessing ---------------------------
__global__ void init_kernel(float* deg, int* counts) {
    int i = blockIdx.x * blockDim.x + threadIdx.x;
    if (i < NNODE) { deg[i] = 2.0f; counts[i] = 1; }   // self-loop fill 2.0
}

__global__ void edge_deg_kernel(const int* __restrict__ ei, const float* __restrict__ ew,
                                float* deg, int* counts) {
    int e = blockIdx.x * blockDim.x + threadIdx.x;
    if (e < NEDGE) {
        int t = ei[NEDGE + e];
        atomicAdd(&deg[t], ew[e]);
        atomicAdd(&counts[t], 1);
    }
}

__global__ void scan_kernel(const float* __restrict__ deg, const int* __restrict__ counts,
                            float* __restrict__ dinv, int* __restrict__ rowptr,
                            int* __restrict__ cursor, int* __restrict__ col,
                            float* __restrict__ val) {
    __shared__ int sc[NNODE];
    int i = threadIdx.x;
    float d = deg[i];
    float di = (d > 0.0f) ? (1.0f / sqrtf(d)) : 0.0f;
    dinv[i] = di;
    int cnt = counts[i];
    sc[i] = cnt;
    __syncthreads();
    for (int ofs = 1; ofs < NNODE; ofs <<= 1) {
        int add = (i >= ofs) ? sc[i - ofs] : 0;
        __syncthreads();
        sc[i] += add;
        __syncthreads();
    }
    int ex = sc[i] - cnt;            // exclusive prefix
    rowptr[i] = ex;
    if (i == NNODE - 1) rowptr[NNODE] = sc[NNODE - 1];
    col[ex] = i;                     // self-loop entry
    val[ex] = di * 2.0f * di;
    cursor[i] = ex + 1;
}

__global__ void fill_kernel(const int* __restrict__ ei, const float* __restrict__ ew,
                            const float* __restrict__ dinv, int* cursor,
                            int* __restrict__ col, float* __restrict__ val) {
    int e = blockIdx.x * blockDim.x + threadIdx.x;
    if (e < NEDGE) {
        int s = ei[e], t = ei[NEDGE + e];
        int p = atomicAdd(&cursor[t], 1);
        col[p] = s;
        val[p] = dinv[s] * ew[e] * dinv[t];
    }
}

// Wf[2j+g][k] = sum_m Wg[k][m]*Lg_top[m][j]; bfold[2j+g] = bg@Lg_top[:,j]+lgb[j]
__global__ void fold_kernel(const float* __restrict__ Wz, const float* __restrict__ lzW,
                            const float* __restrict__ bz, const float* __restrict__ lzb,
                            const float* __restrict__ Wh, const float* __restrict__ lhW,
                            const float* __restrict__ bh, const float* __restrict__ lhb,
                            u16* __restrict__ Wf, float* __restrict__ bfold) {
    int nidx = blockIdx.x;               // 0..511
    int g = nidx & 1, j = nidx >> 1;
    int k = threadIdx.x;                 // 128
    const float* W = g ? Wh : Wz;        // [128][256]
    const float* L = g ? lhW : lzW;      // [512][256], top half used
    float acc = 0.0f;
    for (int m = 0; m < DHID; ++m)
        acc += W[k * DHID + m] * L[m * DHID + j];
    Wf[nidx * DCIN + k] = f2b(acc);
    if (k == 0) {
        const float* bg = g ? bh : bz;
        const float* lb = g ? lhb : lzb;
        float ab = 0.0f;
        for (int m = 0; m < DHID; ++m) ab += bg[m] * L[m * DHID + j];
        bfold[nidx] = ab + lb[j];
    }
}

// --------------- fused TGCN: aggregate + GEMM + cell + l1-dot --------------
// block = (batch b, 64-node tile). hdot[b*512+n] = relu(Hn[b,n,:]) @ l1_W
__global__ __launch_bounds__(256)
void tgcn_kernel(const float* __restrict__ x, const int* __restrict__ rowptr,
                 const int* __restrict__ col, const float* __restrict__ val,
                 const u16* __restrict__ Wf, const float* __restrict__ bfold,
                 const float* __restrict__ l1W, float* __restrict__ hdot) {
    __shared__ u16 As[64][136];          // 64 rows x 128 k (pad 8)
    const int tid = threadIdx.x;
    const int bx = blockIdx.x;
    const int b = bx >> 3;
    const int n0 = (bx & 7) * 64;

    // phase A: aggregate A-tile into LDS (fp32 math, bf16 store; coalesced c)
    {
        const int c = tid & 127;
        const int half = tid >> 7;
        for (int it = 0; it < 32; ++it) {
            int r = it * 2 + half;
            int n = n0 + r;
            int s = rowptr[n], e = rowptr[n + 1];
            float acc = 0.0f;
            for (int i = s; i < e; ++i)
                acc += val[i] * x[((long)b * NNODE + col[i]) * DCIN + c];
            As[r][c] = f2b(acc);
        }
    }
    __syncthreads();

    // phase B: 4 waves; wave w owns M-rows [w*16, w*16+16)
    const int w = tid >> 6, l = tid & 63;
    const int ncol = l & 15, q = l >> 4, ko = q * 8;

    s8v af[4];
    #pragma unroll
    for (int kc = 0; kc < 4; ++kc)
        af[kc] = *(const s8v*)(&As[w * 16 + ncol][kc * 32 + ko]);

    float partial[4] = {0.f, 0.f, 0.f, 0.f};
    for (int nc = 0; nc < 32; ++nc) {
        int n = nc * 16 + ncol;
        const u16* brow = Wf + (long)n * DCIN + ko;
        f4v acc = {0.f, 0.f, 0.f, 0.f};
        #pragma unroll
        for (int kc = 0; kc < 4; ++kc)
            acc = mfma16(af[kc], *(const s8v*)(brow + kc * 32), acc);
        float bias = bfold[n];
        float l1w = l1W[n >> 1];
        #pragma unroll
        for (int rr = 0; rr < 4; ++rr) {
            float v = acc[rr] + bias;
            float o = __shfl_xor(v, 1);              // partner column (z<->h)
            float zpre = (ncol & 1) ? o : v;
            float hpre = (ncol & 1) ? v : o;
            float hn = (1.0f - sigm(zpre)) * tanh_(hpre);
            hn = hn > 0.0f ? hn : 0.0f;
            if (!(ncol & 1)) partial[rr] += hn * l1w; // count each j once
        }
    }
    #pragma unroll
    for (int rr = 0; rr < 4; ++rr) {
        float p = partial[rr];
        p += __shfl_xor(p, 1); p += __shfl_xor(p, 2);
        p += __shfl_xor(p, 4); p += __shfl_xor(p, 8);
        if (ncol == 0)
            hdot[bx * 64 + w * 16 + q * 4 + rr] = p;
    }
}

// ---------------- fused 2-layer GRU recurrence + l2-dot --------------------
// 4 blocks x 16 batches (full M=16 MFMA). h in LDS; bf16 weights streamed
// from L2 each step. gdot[b*512+t] = h2_t[b,:] @ l2_W.
__global__ __launch_bounds__(512)
void gru_kernel(const u16* __restrict__ xb16,
                const u16* __restrict__ Wih0, const u16* __restrict__ Whh0,
                const float* __restrict__ bih0, const float* __restrict__ bhh0,
                const u16* __restrict__ Wih1, const u16* __restrict__ Whh1,
                const float* __restrict__ bih1, const float* __restrict__ bhh1,
                const float* __restrict__ l2W, float* __restrict__ gdot) {
    __shared__ u16   hA[16][264];    // layer0 h, bf16 (pad 8)
    __shared__ u16   hB[16][264];    // layer1 h, bf16
    __shared__ float h0f[16][257];   // layer0 h, fp32
    __shared__ float h1f[16][257];   // layer1 h, fp32
    __shared__ float gpart[8][16];

    const int tid = threadIdx.x;
    const int w = tid >> 6, l = tid & 63;
    const int ncol = l & 15, q = l >> 4, ko = q * 8;
    const int b0 = blockIdx.x * 16;

    for (int i = tid; i < 16 * 264; i += 512) { (&hA[0][0])[i] = 0; (&hB[0][0])[i] = 0; }
    for (int i = tid; i < 16 * 257; i += 512) { (&h0f[0][0])[i] = 0.0f; (&h1f[0][0])[i] = 0.0f; }

    float b0r[2], b0z[2], b0i[2], b0h[2], b1r[2], b1z[2], b1i[2], b1h[2], l2v[2];
    const u16 *wi0[2][3], *wh0[2][3], *wi1[2][3], *wh1[2][3];
    #pragma unroll
    for (int ci = 0; ci < 2; ++ci) {
        int j = (2 * w + ci) * 16 + ncol;
        b0r[ci] = bih0[j]       + bhh0[j];
        b0z[ci] = bih0[256 + j] + bhh0[256 + j];
        b0i[ci] = bih0[512 + j];
        b0h[ci] = bhh0[512 + j];
        b1r[ci] = bih1[j]       + bhh1[j];
        b1z[ci] = bih1[256 + j] + bhh1[256 + j];
        b1i[ci] = bih1[512 + j];
        b1h[ci] = bhh1[512 + j];
        l2v[ci] = l2W[j];
        #pragma unroll
        for (int g = 0; g < 3; ++g) {
            wi0[ci][g] = Wih0 + (long)(g * 256 + j) * DCIN + ko;
            wh0[ci][g] = Whh0 + (long)(g * 256 + j) * DHID + ko;
            wi1[ci][g] = Wih1 + (long)(g * 256 + j) * DHID + ko;
            wh1[ci][g] = Whh1 + (long)(g * 256 + j) * DHID + ko;
        }
    }
    const u16* xp = xb16 + (long)(b0 + ncol) * (NNODE * DCIN) + ko;  // A row = batch
    __syncthreads();

    for (int t = 0; t < NNODE; ++t) {
        // ============ layer 0 ============
        s8v xa[4], ha[8];
        #pragma unroll
        for (int kc = 0; kc < 4; ++kc) xa[kc] = *(const s8v*)(xp + kc * 32);
        #pragma unroll
        for (int kc = 0; kc < 8; ++kc) ha[kc] = *(const s8v*)(&hA[ncol][kc * 32 + ko]);
        __syncthreads();                                   // (1) hA reads done

        f4v aR[2], aZ[2], aI[2], aH[2];
        #pragma unroll
        for (int ci = 0; ci < 2; ++ci) {
            f4v r = {0,0,0,0}, z = {0,0,0,0}, gi = {0,0,0,0}, gh = {0,0,0,0};
            #pragma unroll
            for (int kc = 0; kc < 4; ++kc) {
                r  = mfma16(xa[kc], *(const s8v*)(wi0[ci][0] + kc * 32), r);
                z  = mfma16(xa[kc], *(const s8v*)(wi0[ci][1] + kc * 32), z);
                gi = mfma16(xa[kc], *(const s8v*)(wi0[ci][2] + kc * 32), gi);
            }
            #pragma unroll
            for (int kc = 0; kc < 8; ++kc) {
                r  = mfma16(ha[kc], *(const s8v*)(wh0[ci][0] + kc * 32), r);
                z  = mfma16(ha[kc], *(const s8v*)(wh0[ci][1] + kc * 32), z);
                gh = mfma16(ha[kc], *(const s8v*)(wh0[ci][2] + kc * 32), gh);
            }
            aR[ci] = r; aZ[ci] = z; aI[ci] = gi; aH[ci] = gh;
        }
        #pragma unroll
        for (int ci = 0; ci < 2; ++ci) {
            int j = (2 * w + ci) * 16 + ncol;
            #pragma unroll
            for (int rr = 0; rr < 4; ++rr) {
                int bm = q * 4 + rr;
                float rv = sigm(aR[ci][rr] + b0r[ci]);
                float zv = sigm(aZ[ci][rr] + b0z[ci]);
                float nv = tanh_(aI[ci][rr] + b0i[ci] + rv * (aH[ci][rr] + b0h[ci]));
                float hold = h0f[bm][j];
                float hn = nv + zv * (hold - nv);
                h0f[bm][j] = hn;
                hA[bm][j] = f2b(hn);
            }
        }
        __syncthreads();                                   // (2) hA/h0f written

        // ============ layer 1 ============
        s8v xb[8], hb[8];
        #pragma unroll
        for (int kc = 0; kc < 8; ++kc) {
            xb[kc] = *(const s8v*)(&hA[ncol][kc * 32 + ko]);
            hb[kc] = *(const s8v*)(&hB[ncol][kc * 32 + ko]);
        }
        __syncthreads();                                   // (3) hB reads done

        #pragma unroll
        for (int ci = 0; ci < 2; ++ci) {
            f4v r = {0,0,0,0}, z = {0,0,0,0}, gi = {0,0,0,0}, gh = {0,0,0,0};
            #pragma unroll
            for (int kc = 0; kc < 8; ++kc) {
                r  = mfma16(xb[kc], *(const s8v*)(wi1[ci][0] + kc * 32), r);
                z  = mfma16(xb[kc], *(const s8v*)(wi1[ci][1] + kc * 32), z);
                gi = mfma16(xb[kc], *(const s8v*)(wi1[ci][2] + kc * 32), gi);
            }
            #pragma unroll
            for (int kc = 0; kc < 8; ++kc) {
                r  = mfma16(hb[kc], *(const s8v*)(wh1[ci][0] + kc * 32), r);
                z  = mfma16(hb[kc], *(const s8v*)(wh1[ci][1] + kc * 32), z);
                gh = mfma16(hb[kc], *(const s8v*)(wh1[ci][2] + kc * 32), gh);
            }
            aR[ci] = r; aZ[ci] = z; aI[ci] = gi; aH[ci] = gh;
        }
        float p[4] = {0.f, 0.f, 0.f, 0.f};
        #pragma unroll
        for (int ci = 0; ci < 2; ++ci) {
            int j = (2 * w + ci) * 16 + ncol;
            #pragma unroll
            for (int rr = 0; rr < 4; ++rr) {
                int bm = q * 4 + rr;
                float rv = sigm(aR[ci][rr] + b1r[ci]);
                float zv = sigm(aZ[ci][rr] + b1z[ci]);
                float nv = tanh_(aI[ci][rr] + b1i[ci] + rv * (aH[ci][rr] + b1h[ci]));
                float hold = h1f[bm][j];
                float hn = nv + zv * (hold - nv);
                h1f[bm][j] = hn;
                hB[bm][j] = f2b(hn);
                p[rr] += hn * l2v[ci];
            }
        }
        #pragma unroll
        for (int rr = 0; rr < 4; ++rr) {
            float v = p[rr];
            v += __shfl_xor(v, 1); v += __shfl_xor(v, 2);
            v += __shfl_xor(v, 4); v += __shfl_xor(v, 8);
            if (ncol == 0) gpart[w][q * 4 + rr] = v;
        }
        __syncthreads();                                   // (4) hB/h1f/gpart done
        if (tid < 16) {
            float s = 0.0f;
            #pragma unroll
            for (int ww = 0; ww < 8; ++ww) s += gpart[ww][tid];
            gdot[(long)(b0 + tid) * NNODE + t] = s;
        }
        xp += DCIN;
    }
}

// ------------------------------- final head --------------------------------
__global__ __launch_bounds__(256)
void head_kernel(const float* __restrict__ gdot, const float* __restrict__ hdot,
                 const float* __restrict__ l1b, const float* __restrict__ l2b,
                 const float* __restrict__ l3W, const float* __restrict__ l3b,
                 float* __restrict__ out) {
    int idx = blockIdx.x * 256 + threadIdx.x;
    if (idx >= NBATCH * NNODE * 12) return;
    int r = idx / 12, oc = idx - r * 12;
    float g  = gdot[r] + l2b[0];
    float hh = hdot[r] + l1b[0];
    out[idx] = g * l3W[oc] + hh * l3W[12 + oc] + l3b[oc];
}

// ------------------------------ host launcher ------------------------------

extern "C" void kernel_launch(void* const* d_in, const int* in_sizes, int n_in,
                              void* d_out, int out_size, void* d_ws, size_t ws_size,
                              hipStream_t stream) {
    const float* x    = (const float*)d_in[0];
    const int*   ei   = (const int*)  d_in[1];
    const float* ew   = (const float*)d_in[2];
    const float* Wz   = (const float*)d_in[3];
    const float* bz   = (const float*)d_in[4];
    const float* lzW  = (const float*)d_in[5];
    const float* lzb  = (const float*)d_in[6];
    // d_in[7..10] (TGCN r-gate) unused: H0 == 0
    const float* Wh   = (const float*)d_in[11];
    const float* bh   = (const float*)d_in[12];
    const float* lhW  = (const float*)d_in[13];
    const float* lhb  = (const float*)d_in[14];
    const float* Wih0 = (const float*)d_in[15];
    const float* Whh0 = (const float*)d_in[16];
    const float* bih0 = (const float*)d_in[17];
    const float* bhh0 = (const float*)d_in[18];
    const float* Wih1 = (const float*)d_in[19];
    const float* Whh1 = (const float*)d_in[20];
    const float* bih1 = (const float*)d_in[21];
    const float* bhh1 = (const float*)d_in[22];
    const float* l1W  = (const float*)d_in[23];
    const float* l1b  = (const float*)d_in[24];
    const float* l2W  = (const float*)d_in[25];
    const float* l2b  = (const float*)d_in[26];
    const float* l3W  = (const float*)d_in[27];
    const float* l3b  = (const float*)d_in[28];

    char* ws = (char*)d_ws;
    size_t o = 0;
    auto take = [&](size_t nbytes) {
        char* p = ws + o;
        o = (o + nbytes + 255) & ~(size_t)255;
        return p;
    };
    float* deg    = (float*)take(NNODE * 4);
    float* dinv   = (float*)take(NNODE * 4);
    int*   rowptr = (int*)  take((NNODE + 1) * 4);
    int*   cursor = (int*)  take(NNODE * 4);          // doubles as counts
    int*   col    = (int*)  take((NEDGE + NNODE) * 4);
    float* val    = (float*)take((NEDGE + NNODE) * 4);
    u16*   Wf     = (u16*)  take((size_t)512 * DCIN * 2);
    float* bfold  = (float*)take(512 * 4);
    float* hdot   = (float*)take((size_t)NBATCH * NNODE * 4);
    float* gdot   = (float*)take((size_t)NBATCH * NNODE * 4);
    u16*   xb16   = (u16*)  take((size_t)NBATCH * NNODE * DCIN * 2);  // 8.4 MB
    u16*   Wih0b  = (u16*)  take((size_t)3 * 256 * DCIN * 2);
    u16*   Whh0b  = (u16*)  take((size_t)3 * 256 * DHID * 2);
    u16*   Wih1b  = (u16*)  take((size_t)3 * 256 * DHID * 2);
    u16*   Whh1b  = (u16*)  take((size_t)3 * 256 * DHID * 2);
    if (o > ws_size) return;   // clean-failure signature: absmax == 4.57e-2

    // bf16 conversions (once per call)
    const int nx4 = NBATCH * NNODE * DCIN / 4;
    cvt_kernel<<<(nx4 + 255) / 256, 256, 0, stream>>>(x, xb16, nx4);
    cvt_kernel<<<(3 * 256 * DCIN / 4 + 255) / 256, 256, 0, stream>>>(Wih0, Wih0b, 3 * 256 * DCIN / 4);
    cvt_kernel<<<(3 * 256 * DHID / 4 + 255) / 256, 256, 0, stream>>>(Whh0, Whh0b, 3 * 256 * DHID / 4);
    cvt_kernel<<<(3 * 256 * DHID / 4 + 255) / 256, 256, 0, stream>>>(Wih1, Wih1b, 3 * 256 * DHID / 4);
    cvt_kernel<<<(3 * 256 * DHID / 4 + 255) / 256, 256, 0, stream>>>(Whh1, Whh1b, 3 * 256 * DHID / 4);

    // graph preprocessing
    init_kernel<<<2, 256, 0, stream>>>(deg, cursor);
    edge_deg_kernel<<<NEDGE / 256, 256, 0, stream>>>(ei, ew, deg, cursor);
    scan_kernel<<<1, NNODE, 0, stream>>>(deg, cursor, dinv, rowptr, cursor, col, val);
    fill_kernel<<<NEDGE / 256, 256, 0, stream>>>(ei, ew, dinv, cursor, col, val);
    fold_kernel<<<512, DCIN, 0, stream>>>(Wz, lzW, bz, lzb, Wh, lhW, bh, lhb, Wf, bfold);

    // fused branches
    tgcn_kernel<<<512, 256, 0, stream>>>(x, rowptr, col, val, Wf, bfold, l1W, hdot);
    gru_kernel<<<4, 512, 0, stream>>>(xb16, Wih0b, Whh0b, bih0, bhh0,
                                      Wih1b, Whh1b, bih1, bhh1, l2W, gdot);
    head_kernel<<<(NBATCH * NNODE * 12 + 255) / 256, 256, 0, stream>>>(
        gdot, hdot, l1b, l2b, l3W, l3b, (float*)d_out);
    (void)in_sizes; (void)n_in; (void)out_size;
}

// Round 4
// 16507.053 us; speedup vs baseline: 1.0642x; 1.0642x over previous
//
#include <hip/hip_runtime.h>

// ---------------------------------------------------------------------------
// TGCN2 forward, MI355X gfx950. All float tensors fp32; edge_index i32.
// Math: H0=0 => TGCN R-gate dead, Hn=(1-Z)*H~, concat([c,0])@L == c@L_top;
// A(xW)L == (Ax)(WL) -> folded TGCN gate weights; head dots fused.
// GRU: 2-block producer(L0)/consumer(L1) persistent pipeline, flag-synced
// ring of bf16 h0 packets; weights pre-packed fragment-linear; h fp32 in
// registers; bf16 h exchange via XOR-swizzled 64KB LDS double buffer.
// ---------------------------------------------------------------------------

typedef unsigned short u16;
typedef unsigned long long u64;
typedef short s8v __attribute__((ext_vector_type(8)));
typedef float f4v __attribute__((ext_vector_type(4)));

#define NBATCH 64
#define NNODE  512
#define DCIN   128
#define DHID   256
#define NEDGE  8192
#define RING   8

__device__ __forceinline__ u16 f2b(float f) {
    union { float f; unsigned int i; } v; v.f = f;
    unsigned int x = v.i;
    return (u16)((x + 0x7FFFu + ((x >> 16) & 1u)) >> 16);   // RNE
}
__device__ __forceinline__ float sigm(float x)  { return 1.0f / (1.0f + __expf(-x)); }
__device__ __forceinline__ float tanh_(float x) { return 1.0f - 2.0f / (1.0f + __expf(2.0f * x)); }
__device__ __forceinline__ f4v mfma16(s8v a, s8v b, f4v c) {
    return __builtin_amdgcn_mfma_f32_16x16x32_bf16(a, b, c, 0, 0, 0);
}
// agent-scope per-access coherent 16B ring transfers (no cache-wide invalidates)
__device__ __forceinline__ s8v ld_ring(const u64* p) {
    union { u64 d[2]; s8v v; } u;
    u.d[0] = __hip_atomic_load(p,     __ATOMIC_RELAXED, __HIP_MEMORY_SCOPE_AGENT);
    u.d[1] = __hip_atomic_load(p + 1, __ATOMIC_RELAXED, __HIP_MEMORY_SCOPE_AGENT);
    return u.v;
}
__device__ __forceinline__ void st_ring(u64* p, s8v v) {
    union { s8v v; u64 d[2]; } u; u.v = v;
    __hip_atomic_store(p,     u.d[0], __ATOMIC_RELAXED, __HIP_MEMORY_SCOPE_AGENT);
    __hip_atomic_store(p + 1, u.d[1], __ATOMIC_RELAXED, __HIP_MEMORY_SCOPE_AGENT);
}

// --------------------------- graph preprocessing ---------------------------
__global__ void init_kernel(float* deg, int* counts, int* flags) {
    int i = blockIdx.x * blockDim.x + threadIdx.x;
    if (i < NNODE) { deg[i] = 2.0f; counts[i] = 1; }
    if (i == 0) { flags[0] = 0; flags[1] = 0; }
}

__global__ void edge_deg_kernel(const int* __restrict__ ei, const float* __restrict__ ew,
                                float* deg, int* counts) {
    int e = blockIdx.x * blockDim.x + threadIdx.x;
    if (e < NEDGE) {
        int t = ei[NEDGE + e];
        atomicAdd(&deg[t], ew[e]);
        atomicAdd(&counts[t], 1);
    }
}

__global__ void scan_kernel(const float* __restrict__ deg, const int* __restrict__ counts,
                            float* __restrict__ dinv, int* __restrict__ rowptr,
                            int* __restrict__ cursor, int* __restrict__ col,
                            float* __restrict__ val) {
    __shared__ int sc[NNODE];
    int i = threadIdx.x;
    float d = deg[i];
    float di = (d > 0.0f) ? (1.0f / sqrtf(d)) : 0.0f;
    dinv[i] = di;
    int cnt = counts[i];
    sc[i] = cnt;
    __syncthreads();
    for (int ofs = 1; ofs < NNODE; ofs <<= 1) {
        int add = (i >= ofs) ? sc[i - ofs] : 0;
        __syncthreads();
        sc[i] += add;
        __syncthreads();
    }
    int ex = sc[i] - cnt;
    rowptr[i] = ex;
    if (i == NNODE - 1) rowptr[NNODE] = sc[NNODE - 1];
    col[ex] = i;
    val[ex] = di * 2.0f * di;
    cursor[i] = ex + 1;
}

__global__ void fill_kernel(const int* __restrict__ ei, const float* __restrict__ ew,
                            const float* __restrict__ dinv, int* cursor,
                            int* __restrict__ col, float* __restrict__ val) {
    int e = blockIdx.x * blockDim.x + threadIdx.x;
    if (e < NEDGE) {
        int s = ei[e], t = ei[NEDGE + e];
        int p = atomicAdd(&cursor[t], 1);
        col[p] = s;
        val[p] = dinv[s] * ew[e] * dinv[t];
    }
}

// Wf[2j+g][k] = sum_m Wg[k][m]*Lg_top[m][j]; bfold[2j+g] = bg@Lg_top[:,j]+lgb[j]
__global__ void fold_kernel(const float* __restrict__ Wz, const float* __restrict__ lzW,
                            const float* __restrict__ bz, const float* __restrict__ lzb,
                            const float* __restrict__ Wh, const float* __restrict__ lhW,
                            const float* __restrict__ bh, const float* __restrict__ lhb,
                            u16* __restrict__ Wf, float* __restrict__ bfold) {
    int nidx = blockIdx.x;
    int g = nidx & 1, j = nidx >> 1;
    int k = threadIdx.x;
    const float* W = g ? Wh : Wz;
    const float* L = g ? lhW : lzW;
    float acc = 0.0f;
    for (int m = 0; m < DHID; ++m)
        acc += W[k * DHID + m] * L[m * DHID + j];
    Wf[nidx * DCIN + k] = f2b(acc);
    if (k == 0) {
        const float* bg = g ? bh : bz;
        const float* lb = g ? lhb : lzb;
        float ab = 0.0f;
        for (int m = 0; m < DHID; ++m) ab += bg[m] * L[m * DHID + j];
        bfold[nidx] = ab + lb[j];
    }
}

// ----------------------------- weight repacks ------------------------------
// dst fragment-linear: flat = ((r*KC + kc)*3 + g)*512 + l*8 ; r = j-slice 0..15
__global__ void repack_w_kernel(const float* __restrict__ Wih, const float* __restrict__ Whh,
                                int KCX, int KC, int KX, int KH, u16* __restrict__ dst) {
    int id = blockIdx.x * 256 + threadIdx.x;
    int total = 16 * KC * 3 * 64;
    if (id >= total) return;
    int l = id & 63; int rest = id >> 6;
    int g = rest % 3; rest /= 3;
    int kc = rest % KC; rest /= KC;
    int r = rest;
    int j = r * 16 + (l & 15);
    int q = l >> 4;
    const float* src; int k;
    if (kc < KCX) { src = Wih + (size_t)(g * 256 + j) * KX; k = kc * 32 + q * 8; }
    else          { src = Whh + (size_t)(g * 256 + j) * KH; k = (kc - KCX) * 32 + q * 8; }
    u16* d = dst + (((size_t)(r * KC + kc)) * 3 + g) * 512 + l * 8;
    #pragma unroll
    for (int e = 0; e < 8; ++e) d[e] = f2b(src[k + e]);
}

// xpack[t][Mt][kc][lane][8]: A-fragment-linear bf16 x
__global__ void repack_x_kernel(const float* __restrict__ x, u16* __restrict__ xpack) {
    int id = blockIdx.x * 256 + threadIdx.x;       // 512*4*4*64 = 524288
    int l = id & 63; int rest = id >> 6;
    int kc = rest & 3; rest >>= 2;
    int Mt = rest & 3; rest >>= 2;
    int t = rest;
    int b = Mt * 16 + (l & 15);
    int c = kc * 32 + (l >> 4) * 8;
    const float* s = x + ((size_t)b * NNODE + t) * DCIN + c;
    u16* d = xpack + (((size_t)t * 4 + Mt) * 4 + kc) * 512 + (size_t)l * 8;
    #pragma unroll
    for (int e = 0; e < 8; ++e) d[e] = f2b(s[e]);
}

// --------------- fused TGCN: aggregate + GEMM + cell + l1-dot --------------
__global__ __launch_bounds__(256)
void tgcn_kernel(const float* __restrict__ x, const int* __restrict__ rowptr,
                 const int* __restrict__ col, const float* __restrict__ val,
                 const u16* __restrict__ Wf, const float* __restrict__ bfold,
                 const float* __restrict__ l1W, float* __restrict__ hdot) {
    __shared__ u16 As[64][136];
    const int tid = threadIdx.x;
    const int bx = blockIdx.x;
    const int b = bx >> 3;
    const int n0 = (bx & 7) * 64;
    {
        const int c = tid & 127;
        const int half = tid >> 7;
        for (int it = 0; it < 32; ++it) {
            int r = it * 2 + half;
            int n = n0 + r;
            int s = rowptr[n], e = rowptr[n + 1];
            float acc = 0.0f;
            for (int i = s; i < e; ++i)
                acc += val[i] * x[((size_t)b * NNODE + col[i]) * DCIN + c];
            As[r][c] = f2b(acc);
        }
    }
    __syncthreads();
    const int w = tid >> 6, l = tid & 63;
    const int ncol = l & 15, q = l >> 4, ko = q * 8;
    s8v af[4];
    #pragma unroll
    for (int kc = 0; kc < 4; ++kc)
        af[kc] = *(const s8v*)(&As[w * 16 + ncol][kc * 32 + ko]);
    float partial[4] = {0.f, 0.f, 0.f, 0.f};
    for (int nc = 0; nc < 32; ++nc) {
        int n = nc * 16 + ncol;
        const u16* brow = Wf + (size_t)n * DCIN + ko;
        f4v acc = {0.f, 0.f, 0.f, 0.f};
        #pragma unroll
        for (int kc = 0; kc < 4; ++kc)
            acc = mfma16(af[kc], *(const s8v*)(brow + kc * 32), acc);
        float bias = bfold[n];
        float l1w = l1W[n >> 1];
        #pragma unroll
        for (int rr = 0; rr < 4; ++rr) {
            float v = acc[rr] + bias;
            float o = __shfl_xor(v, 1);
            float zpre = (ncol & 1) ? o : v;
            float hpre = (ncol & 1) ? v : o;
            float hn = (1.0f - sigm(zpre)) * tanh_(hpre);
            hn = hn > 0.0f ? hn : 0.0f;
            if (!(ncol & 1)) partial[rr] += hn * l1w;
        }
    }
    #pragma unroll
    for (int rr = 0; rr < 4; ++rr) {
        float p = partial[rr];
        p += __shfl_xor(p, 1); p += __shfl_xor(p, 2);
        p += __shfl_xor(p, 4); p += __shfl_xor(p, 8);
        if (ncol == 0)
            hdot[bx * 64 + w * 16 + q * 4 + rr] = p;
    }
}

// ---------------- GRU: 2-block producer/consumer pipeline ------------------
// block 0: layer0 (K=128 x + 256 h); block 1: layer1 (K=256 h0 + 256 h1).
// h16s: XOR-swizzled bf16 h, double-buffered, [buf][b*256 + swz]. 64KB LDS.
__global__ __launch_bounds__(512, 2)
void gru_pipe_kernel(const u16* __restrict__ xpack,
                     const u16* __restrict__ Wpk0, const u16* __restrict__ Wpk1,
                     const float* __restrict__ bih0, const float* __restrict__ bhh0,
                     const float* __restrict__ bih1, const float* __restrict__ bhh1,
                     const float* __restrict__ l2W, u16* __restrict__ ring,
                     int* flags, float* __restrict__ gpartg) {
    __shared__ u16 h16s[2][64 * 256];
    const int tid = threadIdx.x;
    const int w = tid >> 6, l = tid & 63;
    const int ncol = l & 15, q = l >> 4;
    int* flagP = flags;
    int* flagC = flags + 1;

    for (int i = tid; i < 2 * 64 * 256; i += 512) (&h16s[0][0])[i] = 0;
    __syncthreads();

    // swizzled element address: row b (0..63), col j (0..255)
    #define HPTR(buf, b, j) (&h16s[buf][(b) * 256 + (((j) >> 3) ^ ((b) & 7)) * 8 + ((j) & 7)])

    if (blockIdx.x == 0) {
        // ============================ producer: layer 0 =====================
        float br[2], bz[2], bi[2], bh[2];
        const u16* wb[2];
        #pragma unroll
        for (int ci = 0; ci < 2; ++ci) {
            int j = (2 * w + ci) * 16 + ncol;
            br[ci] = bih0[j] + bhh0[j];
            bz[ci] = bih0[256 + j] + bhh0[256 + j];
            bi[ci] = bih0[512 + j];
            bh[ci] = bhh0[512 + j];
            wb[ci] = Wpk0 + (size_t)(w * 2 + ci) * (12 * 3 * 512);
        }
        float hreg[2][16];
        #pragma unroll
        for (int ci = 0; ci < 2; ++ci)
            #pragma unroll
            for (int i = 0; i < 16; ++i) hreg[ci][i] = 0.0f;

        for (int t = 0; t < NNODE; ++t) {
            const int p = t & 1;
            if (t >= RING) {
                while (__hip_atomic_load(flagC, __ATOMIC_RELAXED, __HIP_MEMORY_SCOPE_AGENT) < t - RING + 1)
                    __builtin_amdgcn_s_sleep(8);
                asm volatile("" ::: "memory");
            }
            const u16* xb = xpack + (size_t)t * 8192;
            #pragma unroll
            for (int ci = 0; ci < 2; ++ci) {
                f4v aR[4], aZ[4], aNi[4], aNh[4];
                #pragma unroll
                for (int Mt = 0; Mt < 4; ++Mt) {
                    aR[Mt] = f4v{0,0,0,0}; aZ[Mt] = f4v{0,0,0,0};
                    aNi[Mt] = f4v{0,0,0,0}; aNh[Mt] = f4v{0,0,0,0};
                }
                const u16* wp = wb[ci];
                #pragma unroll
                for (int kc = 0; kc < 4; ++kc) {            // x part
                    s8v a[4];
                    #pragma unroll
                    for (int Mt = 0; Mt < 4; ++Mt)
                        a[Mt] = *(const s8v*)(xb + (Mt * 4 + kc) * 512 + l * 8);
                    s8v bRv = *(const s8v*)(wp + (kc * 3 + 0) * 512 + l * 8);
                    s8v bZv = *(const s8v*)(wp + (kc * 3 + 1) * 512 + l * 8);
                    s8v bNv = *(const s8v*)(wp + (kc * 3 + 2) * 512 + l * 8);
                    #pragma unroll
                    for (int Mt = 0; Mt < 4; ++Mt) {
                        aR[Mt]  = mfma16(a[Mt], bRv, aR[Mt]);
                        aZ[Mt]  = mfma16(a[Mt], bZv, aZ[Mt]);
                        aNi[Mt] = mfma16(a[Mt], bNv, aNi[Mt]);
                    }
                }
                #pragma unroll
                for (int kh = 0; kh < 8; ++kh) {            // h part
                    s8v a[4];
                    #pragma unroll
                    for (int Mt = 0; Mt < 4; ++Mt)
                        a[Mt] = *(const s8v*)HPTR(p, Mt * 16 + ncol, kh * 32 + q * 8);
                    int kc = 4 + kh;
                    s8v bRv = *(const s8v*)(wp + (kc * 3 + 0) * 512 + l * 8);
                    s8v bZv = *(const s8v*)(wp + (kc * 3 + 1) * 512 + l * 8);
                    s8v bNv = *(const s8v*)(wp + (kc * 3 + 2) * 512 + l * 8);
                    #pragma unroll
                    for (int Mt = 0; Mt < 4; ++Mt) {
                        aR[Mt]  = mfma16(a[Mt], bRv, aR[Mt]);
                        aZ[Mt]  = mfma16(a[Mt], bZv, aZ[Mt]);
                        aNh[Mt] = mfma16(a[Mt], bNv, aNh[Mt]);
                    }
                }
                #pragma unroll
                for (int Mt = 0; Mt < 4; ++Mt)
                    #pragma unroll
                    for (int rr = 0; rr < 4; ++rr) {
                        float rv = sigm(aR[Mt][rr] + br[ci]);
                        float zv = sigm(aZ[Mt][rr] + bz[ci]);
                        float nv = tanh_(aNi[Mt][rr] + bi[ci] + rv * (aNh[Mt][rr] + bh[ci]));
                        float ho = hreg[ci][Mt * 4 + rr];
                        float hn = nv + zv * (ho - nv);
                        hreg[ci][Mt * 4 + rr] = hn;
                        *HPTR(1 - p, Mt * 16 + q * 4 + rr, (2 * w + ci) * 16 + ncol) = f2b(hn);
                    }
            }
            __syncthreads();                                // h16[1-p] complete
            // pack h0(t) -> ring slot (fragment-linear, agent-coherent stores)
            u64* slot = (u64*)(ring + (size_t)(t & (RING - 1)) * 16384);
            #pragma unroll
            for (int it = 0; it < 4; ++it) {
                int idx = tid + it * 512;                   // 0..2047
                int f = idx >> 6, ll = idx & 63;
                int Mt = f >> 3, kc = f & 7;
                s8v v = *(const s8v*)HPTR(1 - p, Mt * 16 + (ll & 15), kc * 32 + ((ll >> 4) & 3) * 8);
                st_ring(slot + (size_t)idx * 2, v);
            }
            __syncthreads();                                // stores drained (vmcnt)
            if (tid == 0)
                __hip_atomic_store(flagP, t + 1, __ATOMIC_RELAXED, __HIP_MEMORY_SCOPE_AGENT);
        }
    } else {
        // ============================ consumer: layer 1 =====================
        float br[2], bz[2], bi[2], bh[2], l2v[2];
        const u16* wb[2];
        #pragma unroll
        for (int ci = 0; ci < 2; ++ci) {
            int j = (2 * w + ci) * 16 + ncol;
            br[ci] = bih1[j] + bhh1[j];
            bz[ci] = bih1[256 + j] + bhh1[256 + j];
            bi[ci] = bih1[512 + j];
            bh[ci] = bhh1[512 + j];
            l2v[ci] = l2W[j];
            wb[ci] = Wpk1 + (size_t)(w * 2 + ci) * (16 * 3 * 512);
        }
        float hreg[2][16];
        #pragma unroll
        for (int ci = 0; ci < 2; ++ci)
            #pragma unroll
            for (int i = 0; i < 16; ++i) hreg[ci][i] = 0.0f;

        for (int t = 0; t < NNODE; ++t) {
            const int p = t & 1;
            if (t > 0 && tid == 0)
                __hip_atomic_store(flagC, t, __ATOMIC_RELAXED, __HIP_MEMORY_SCOPE_AGENT);
            while (__hip_atomic_load(flagP, __ATOMIC_RELAXED, __HIP_MEMORY_SCOPE_AGENT) < t + 1)
                __builtin_amdgcn_s_sleep(8);
            asm volatile("" ::: "memory");
            const u64* slot = (const u64*)(ring + (size_t)(t & (RING - 1)) * 16384);
            float pp[16];
            #pragma unroll
            for (int i = 0; i < 16; ++i) pp[i] = 0.0f;

            #pragma unroll
            for (int ci = 0; ci < 2; ++ci) {
                f4v aR[4], aZ[4], aNi[4], aNh[4];
                #pragma unroll
                for (int Mt = 0; Mt < 4; ++Mt) {
                    aR[Mt] = f4v{0,0,0,0}; aZ[Mt] = f4v{0,0,0,0};
                    aNi[Mt] = f4v{0,0,0,0}; aNh[Mt] = f4v{0,0,0,0};
                }
                const u16* wp = wb[ci];
                #pragma unroll
                for (int kc = 0; kc < 8; ++kc) {            // h0(t) part (ring)
                    s8v a[4];
                    #pragma unroll
                    for (int Mt = 0; Mt < 4; ++Mt)
                        a[Mt] = ld_ring(slot + (size_t)(Mt * 8 + kc) * 128 + l * 2);
                    s8v bRv = *(const s8v*)(wp + (kc * 3 + 0) * 512 + l * 8);
                    s8v bZv = *(const s8v*)(wp + (kc * 3 + 1) * 512 + l * 8);
                    s8v bNv = *(const s8v*)(wp + (kc * 3 + 2) * 512 + l * 8);
                    #pragma unroll
                    for (int Mt = 0; Mt < 4; ++Mt) {
                        aR[Mt]  = mfma16(a[Mt], bRv, aR[Mt]);
                        aZ[Mt]  = mfma16(a[Mt], bZv, aZ[Mt]);
                        aNi[Mt] = mfma16(a[Mt], bNv, aNi[Mt]);
                    }
                }
                #pragma unroll
                for (int kh = 0; kh < 8; ++kh) {            // h1(t-1) part (LDS)
                    s8v a[4];
                    #pragma unroll
                    for (int Mt = 0; Mt < 4; ++Mt)
                        a[Mt] = *(const s8v*)HPTR(p, Mt * 16 + ncol, kh * 32 + q * 8);
                    int kc = 8 + kh;
                    s8v bRv = *(const s8v*)(wp + (kc * 3 + 0) * 512 + l * 8);
                    s8v bZv = *(const s8v*)(wp + (kc * 3 + 1) * 512 + l * 8);
                    s8v bNv = *(const s8v*)(wp + (kc * 3 + 2) * 512 + l * 8);
                    #pragma unroll
                    for (int Mt = 0; Mt < 4; ++Mt) {
                        aR[Mt]  = mfma16(a[Mt], bRv, aR[Mt]);
                        aZ[Mt]  = mfma16(a[Mt], bZv, aZ[Mt]);
                        aNh[Mt] = mfma16(a[Mt], bNv, aNh[Mt]);
                    }
                }
                #pragma unroll
                for (int Mt = 0; Mt < 4; ++Mt)
                    #pragma unroll
                    for (int rr = 0; rr < 4; ++rr) {
                        float rv = sigm(aR[Mt][rr] + br[ci]);
                        float zv = sigm(aZ[Mt][rr] + bz[ci]);
                        float nv = tanh_(aNi[Mt][rr] + bi[ci] + rv * (aNh[Mt][rr] + bh[ci]));
                        float ho = hreg[ci][Mt * 4 + rr];
                        float hn = nv + zv * (ho - nv);
                        hreg[ci][Mt * 4 + rr] = hn;
                        *HPTR(1 - p, Mt * 16 + q * 4 + rr, (2 * w + ci) * 16 + ncol) = f2b(hn);
                        pp[Mt * 4 + rr] += hn * l2v[ci];
                    }
            }
            // reduce l2-dot partials over the 16 ncol lanes; store per-wave
            #pragma unroll
            for (int i = 0; i < 16; ++i) {
                float v = pp[i];
                v += __shfl_xor(v, 1); v += __shfl_xor(v, 2);
                v += __shfl_xor(v, 4); v += __shfl_xor(v, 8);
                pp[i] = v;
            }
            if (ncol == 0) {
                #pragma unroll
                for (int Mt = 0; Mt < 4; ++Mt)
                    #pragma unroll
                    for (int rr = 0; rr < 4; ++rr)
                        gpartg[((size_t)t * 8 + w) * 64 + Mt * 16 + q * 4 + rr] = pp[Mt * 4 + rr];
            }
            __syncthreads();                                // h16[1-p] visible next step
        }
    }
    #undef HPTR
}

// ------------------------------- final head --------------------------------
__global__ __launch_bounds__(256)
void head_kernel(const float* __restrict__ gpartg, const float* __restrict__ hdot,
                 const float* __restrict__ l1b, const float* __restrict__ l2b,
                 const float* __restrict__ l3W, const float* __restrict__ l3b,
                 float* __restrict__ out) {
    int idx = blockIdx.x * 256 + threadIdx.x;
    if (idx >= NBATCH * NNODE * 12) return;
    int r = idx / 12, oc = idx - r * 12;
    int b = r >> 9, n = r & 511;
    float g = 0.0f;
    #pragma unroll
    for (int w = 0; w < 8; ++w) g += gpartg[((size_t)n * 8 + w) * 64 + b];
    g += l2b[0];
    float hh = hdot[r] + l1b[0];
    out[idx] = g * l3W[oc] + hh * l3W[12 + oc] + l3b[oc];
}

// ------------------------------ host launcher ------------------------------
extern "C" void kernel_launch(void* const* d_in, const int* in_sizes, int n_in,
                              void* d_out, int out_size, void* d_ws, size_t ws_size,
                              hipStream_t stream) {
    const float* x    = (const float*)d_in[0];
    const int*   ei   = (const int*)  d_in[1];
    const float* ew   = (const float*)d_in[2];
    const float* Wz   = (const float*)d_in[3];
    const float* bz   = (const float*)d_in[4];
    const float* lzW  = (const float*)d_in[5];
    const float* lzb  = (const float*)d_in[6];
    // d_in[7..10] (TGCN r-gate) unused: H0 == 0
    const float* Wh   = (const float*)d_in[11];
    const float* bh   = (const float*)d_in[12];
    const float* lhW  = (const float*)d_in[13];
    const float* lhb  = (const float*)d_in[14];
    const float* Wih0 = (const float*)d_in[15];
    const float* Whh0 = (const float*)d_in[16];
    const float* bih0 = (const float*)d_in[17];
    const float* bhh0 = (const float*)d_in[18];
    const float* Wih1 = (const float*)d_in[19];
    const float* Whh1 = (const float*)d_in[20];
    const float* bih1 = (const float*)d_in[21];
    const float* bhh1 = (const float*)d_in[22];
    const float* l1W  = (const float*)d_in[23];
    const float* l1b  = (const float*)d_in[24];
    const float* l2W  = (const float*)d_in[25];
    const float* l2b  = (const float*)d_in[26];
    const float* l3W  = (const float*)d_in[27];
    const float* l3b  = (const float*)d_in[28];

    char* ws = (char*)d_ws;
    size_t o = 0;
    auto take = [&](size_t nbytes) {
        char* p = ws + o;
        o = (o + nbytes + 255) & ~(size_t)255;
        return p;
    };
    float* deg    = (float*)take(NNODE * 4);
    float* dinv   = (float*)take(NNODE * 4);
    int*   rowptr = (int*)  take((NNODE + 1) * 4);
    int*   cursor = (int*)  take(NNODE * 4);
    int*   col    = (int*)  take((NEDGE + NNODE) * 4);
    float* val    = (float*)take((NEDGE + NNODE) * 4);
    u16*   Wf     = (u16*)  take((size_t)512 * DCIN * 2);
    float* bfold  = (float*)take(512 * 4);
    float* hdot   = (float*)take((size_t)NBATCH * NNODE * 4);
    float* gpartg = (float*)take((size_t)NNODE * 8 * 64 * 4);          // 1 MB
    u16*   xpack  = (u16*)  take((size_t)NNODE * 4 * 4 * 512 * 2);     // 8.4 MB
    u16*   Wpk0   = (u16*)  take((size_t)16 * 12 * 3 * 512 * 2);       // 590 KB
    u16*   Wpk1   = (u16*)  take((size_t)16 * 16 * 3 * 512 * 2);       // 786 KB
    u16*   ring   = (u16*)  take((size_t)RING * 16384 * 2);            // 256 KB
    int*   flags  = (int*)  take(256);
    if (o > ws_size) return;   // clean-failure signature: absmax == 4.57e-2

    // preprocessing + repacks (flags MUST be zeroed before gru_pipe)
    init_kernel<<<2, 256, 0, stream>>>(deg, cursor, flags);
    edge_deg_kernel<<<NEDGE / 256, 256, 0, stream>>>(ei, ew, deg, cursor);
    scan_kernel<<<1, NNODE, 0, stream>>>(deg, cursor, dinv, rowptr, cursor, col, val);
    fill_kernel<<<NEDGE / 256, 256, 0, stream>>>(ei, ew, dinv, cursor, col, val);
    fold_kernel<<<512, DCIN, 0, stream>>>(Wz, lzW, bz, lzb, Wh, lhW, bh, lhb, Wf, bfold);
    repack_w_kernel<<<(16 * 12 * 3 * 64 + 255) / 256, 256, 0, stream>>>(
        Wih0, Whh0, 4, 12, DCIN, DHID, Wpk0);
    repack_w_kernel<<<(16 * 16 * 3 * 64 + 255) / 256, 256, 0, stream>>>(
        Wih1, Whh1, 8, 16, DHID, DHID, Wpk1);
    repack_x_kernel<<<(NNODE * 4 * 4 * 64) / 256, 256, 0, stream>>>(x, xpack);

    // fused branches
    tgcn_kernel<<<512, 256, 0, stream>>>(x, rowptr, col, val, Wf, bfold, l1W, hdot);
    gru_pipe_kernel<<<2, 512, 0, stream>>>(xpack, Wpk0, Wpk1, bih0, bhh0,
                                           bih1, bhh1, l2W, ring, flags, gpartg);
    head_kernel<<<(NBATCH * NNODE * 12 + 255) / 256, 256, 0, stream>>>(
        gpartg, hdot, l1b, l2b, l3W, l3b, (float*)d_out);
    (void)in_sizes; (void)n_in; (void)out_size;
}

// Round 5
// 2991.023 us; speedup vs baseline: 5.8730x; 5.5189x over previous
//
#include <hip/hip_runtime.h>

// ---------------------------------------------------------------------------
// TGCN2 forward, MI355X gfx950. All float tensors fp32; edge_index i32.
// Math: H0=0 => TGCN R-gate dead, Hn=(1-Z)*H~, concat([c,0])@L == c@L_top;
// A(xW)L == (Ax)(WL) -> folded TGCN gate weights; head dots fused.
// GRU: 32-block spatial pipeline (16 blocks/layer, 16 output channels each).
// Weight slices LDS-resident (loaded once). h exchanged via agent-scope
// fragment-linear rings + per-block flags. fp32 h carried in registers.
// ---------------------------------------------------------------------------

typedef unsigned short u16;
typedef unsigned long long u64;
typedef short s8v __attribute__((ext_vector_type(8)));
typedef float f4v __attribute__((ext_vector_type(4)));

#define NBATCH 64
#define NNODE  512
#define DCIN   128
#define DHID   256
#define NEDGE  8192
#define RING   8
#define SLOTU16 16384   // 32KB per ring slot: 4 Mt x 8 kc x 1024B fragments

__device__ __forceinline__ u16 f2b(float f) {
    union { float f; unsigned int i; } v; v.f = f;
    unsigned int x = v.i;
    return (u16)((x + 0x7FFFu + ((x >> 16) & 1u)) >> 16);   // RNE
}
__device__ __forceinline__ float sigm(float x)  { return 1.0f / (1.0f + __expf(-x)); }
__device__ __forceinline__ float tanh_(float x) { return 1.0f - 2.0f / (1.0f + __expf(2.0f * x)); }
__device__ __forceinline__ f4v mfma16(s8v a, s8v b, f4v c) {
    return __builtin_amdgcn_mfma_f32_16x16x32_bf16(a, b, c, 0, 0, 0);
}
__device__ __forceinline__ s8v ld_ring(const u64* p) {
    union { u64 d[2]; s8v v; } u;
    u.d[0] = __hip_atomic_load(p,     __ATOMIC_RELAXED, __HIP_MEMORY_SCOPE_AGENT);
    u.d[1] = __hip_atomic_load(p + 1, __ATOMIC_RELAXED, __HIP_MEMORY_SCOPE_AGENT);
    return u.v;
}
__device__ __forceinline__ void st_ring(u64* p, s8v v) {
    union { s8v v; u64 d[2]; } u; u.v = v;
    __hip_atomic_store(p,     u.d[0], __ATOMIC_RELAXED, __HIP_MEMORY_SCOPE_AGENT);
    __hip_atomic_store(p + 1, u.d[1], __ATOMIC_RELAXED, __HIP_MEMORY_SCOPE_AGENT);
}

// --------------------------- graph preprocessing ---------------------------
__global__ void init_kernel(float* deg, int* counts, int* flags) {
    int i = blockIdx.x * blockDim.x + threadIdx.x;
    if (i < NNODE) { deg[i] = 2.0f; counts[i] = 1; }
    if (i < 32) flags[i] = 0;
}

__global__ void edge_deg_kernel(const int* __restrict__ ei, const float* __restrict__ ew,
                                float* deg, int* counts) {
    int e = blockIdx.x * blockDim.x + threadIdx.x;
    if (e < NEDGE) {
        int t = ei[NEDGE + e];
        atomicAdd(&deg[t], ew[e]);
        atomicAdd(&counts[t], 1);
    }
}

__global__ void scan_kernel(const float* __restrict__ deg, const int* __restrict__ counts,
                            float* __restrict__ dinv, int* __restrict__ rowptr,
                            int* __restrict__ cursor, int* __restrict__ col,
                            float* __restrict__ val) {
    __shared__ int sc[NNODE];
    int i = threadIdx.x;
    float d = deg[i];
    float di = (d > 0.0f) ? (1.0f / sqrtf(d)) : 0.0f;
    dinv[i] = di;
    int cnt = counts[i];
    sc[i] = cnt;
    __syncthreads();
    for (int ofs = 1; ofs < NNODE; ofs <<= 1) {
        int add = (i >= ofs) ? sc[i - ofs] : 0;
        __syncthreads();
        sc[i] += add;
        __syncthreads();
    }
    int ex = sc[i] - cnt;
    rowptr[i] = ex;
    if (i == NNODE - 1) rowptr[NNODE] = sc[NNODE - 1];
    col[ex] = i;
    val[ex] = di * 2.0f * di;
    cursor[i] = ex + 1;
}

__global__ void fill_kernel(const int* __restrict__ ei, const float* __restrict__ ew,
                            const float* __restrict__ dinv, int* cursor,
                            int* __restrict__ col, float* __restrict__ val) {
    int e = blockIdx.x * blockDim.x + threadIdx.x;
    if (e < NEDGE) {
        int s = ei[e], t = ei[NEDGE + e];
        int p = atomicAdd(&cursor[t], 1);
        col[p] = s;
        val[p] = dinv[s] * ew[e] * dinv[t];
    }
}

// Wf[2j+g][k] = sum_m Wg[k][m]*Lg_top[m][j]; bfold[2j+g] = bg@Lg_top[:,j]+lgb[j]
__global__ void fold_kernel(const float* __restrict__ Wz, const float* __restrict__ lzW,
                            const float* __restrict__ bz, const float* __restrict__ lzb,
                            const float* __restrict__ Wh, const float* __restrict__ lhW,
                            const float* __restrict__ bh, const float* __restrict__ lhb,
                            u16* __restrict__ Wf, float* __restrict__ bfold) {
    int nidx = blockIdx.x;
    int g = nidx & 1, j = nidx >> 1;
    int k = threadIdx.x;
    const float* W = g ? Wh : Wz;
    const float* L = g ? lhW : lzW;
    float acc = 0.0f;
    for (int m = 0; m < DHID; ++m)
        acc += W[k * DHID + m] * L[m * DHID + j];
    Wf[nidx * DCIN + k] = f2b(acc);
    if (k == 0) {
        const float* bg = g ? bh : bz;
        const float* lb = g ? lhb : lzb;
        float ab = 0.0f;
        for (int m = 0; m < DHID; ++m) ab += bg[m] * L[m * DHID + j];
        bfold[nidx] = ab + lb[j];
    }
}

// ----------------------------- weight repacks ------------------------------
// dst fragment-linear: flat = ((r*KC + kc)*3 + g)*512 + l*8 ; r = 16-j slice
__global__ void repack_w_kernel(const float* __restrict__ Wih, const float* __restrict__ Whh,
                                int KCX, int KC, int KX, int KH, u16* __restrict__ dst) {
    int id = blockIdx.x * 256 + threadIdx.x;
    int total = 16 * KC * 3 * 64;
    if (id >= total) return;
    int l = id & 63; int rest = id >> 6;
    int g = rest % 3; rest /= 3;
    int kc = rest % KC; rest /= KC;
    int r = rest;
    int j = r * 16 + (l & 15);
    int q = l >> 4;
    const float* src; int k;
    if (kc < KCX) { src = Wih + (size_t)(g * 256 + j) * KX; k = kc * 32 + q * 8; }
    else          { src = Whh + (size_t)(g * 256 + j) * KH; k = (kc - KCX) * 32 + q * 8; }
    u16* d = dst + (((size_t)(r * KC + kc)) * 3 + g) * 512 + l * 8;
    #pragma unroll
    for (int e = 0; e < 8; ++e) d[e] = f2b(src[k + e]);
}

// xpack[t][Mt][kc][lane][8]: A-fragment-linear bf16 x
__global__ void repack_x_kernel(const float* __restrict__ x, u16* __restrict__ xpack) {
    int id = blockIdx.x * 256 + threadIdx.x;       // 512*4*4*64 = 524288
    int l = id & 63; int rest = id >> 6;
    int kc = rest & 3; rest >>= 2;
    int Mt = rest & 3; rest >>= 2;
    int t = rest;
    int b = Mt * 16 + (l & 15);
    int c = kc * 32 + (l >> 4) * 8;
    const float* s = x + ((size_t)b * NNODE + t) * DCIN + c;
    u16* d = xpack + (((size_t)t * 4 + Mt) * 4 + kc) * 512 + (size_t)l * 8;
    #pragma unroll
    for (int e = 0; e < 8; ++e) d[e] = f2b(s[e]);
}

// --------------- fused TGCN: aggregate + GEMM + cell + l1-dot --------------
__global__ __launch_bounds__(256)
void tgcn_kernel(const float* __restrict__ x, const int* __restrict__ rowptr,
                 const int* __restrict__ col, const float* __restrict__ val,
                 const u16* __restrict__ Wf, const float* __restrict__ bfold,
                 const float* __restrict__ l1W, float* __restrict__ hdot) {
    __shared__ u16 As[64][136];
    const int tid = threadIdx.x;
    const int bx = blockIdx.x;
    const int b = bx >> 3;
    const int n0 = (bx & 7) * 64;
    {
        const int c = tid & 127;
        const int half = tid >> 7;
        for (int it = 0; it < 32; ++it) {
            int r = it * 2 + half;
            int n = n0 + r;
            int s = rowptr[n], e = rowptr[n + 1];
            float acc = 0.0f;
            for (int i = s; i < e; ++i)
                acc += val[i] * x[((size_t)b * NNODE + col[i]) * DCIN + c];
            As[r][c] = f2b(acc);
        }
    }
    __syncthreads();
    const int w = tid >> 6, l = tid & 63;
    const int ncol = l & 15, q = l >> 4, ko = q * 8;
    s8v af[4];
    #pragma unroll
    for (int kc = 0; kc < 4; ++kc)
        af[kc] = *(const s8v*)(&As[w * 16 + ncol][kc * 32 + ko]);
    float partial[4] = {0.f, 0.f, 0.f, 0.f};
    for (int nc = 0; nc < 32; ++nc) {
        int n = nc * 16 + ncol;
        const u16* brow = Wf + (size_t)n * DCIN + ko;
        f4v acc = {0.f, 0.f, 0.f, 0.f};
        #pragma unroll
        for (int kc = 0; kc < 4; ++kc)
            acc = mfma16(af[kc], *(const s8v*)(brow + kc * 32), acc);
        float bias = bfold[n];
        float l1w = l1W[n >> 1];
        #pragma unroll
        for (int rr = 0; rr < 4; ++rr) {
            float v = acc[rr] + bias;
            float o = __shfl_xor(v, 1);
            float zpre = (ncol & 1) ? o : v;
            float hpre = (ncol & 1) ? v : o;
            float hn = (1.0f - sigm(zpre)) * tanh_(hpre);
            hn = hn > 0.0f ? hn : 0.0f;
            if (!(ncol & 1)) partial[rr] += hn * l1w;
        }
    }
    #pragma unroll
    for (int rr = 0; rr < 4; ++rr) {
        float p = partial[rr];
        p += __shfl_xor(p, 1); p += __shfl_xor(p, 2);
        p += __shfl_xor(p, 4); p += __shfl_xor(p, 8);
        if (ncol == 0)
            hdot[bx * 64 + w * 16 + q * 4 + rr] = p;
    }
}

// ------------------- GRU: 32-block spatial pipeline ------------------------
template <int KCX, int KC>
__device__ __forceinline__ void mfma_step(const s8v* wf, const s8v* a0, const s8v* a1,
                                          int l, bool has_h,
                                          f4v& accR, f4v& accZ, f4v& accNi, f4v& accNh) {
    #pragma unroll
    for (int kc = 0; kc < KCX; ++kc) {          // input part (x or h0(t))
        s8v bR = wf[(kc * 3 + 0) * 64 + l];
        s8v bZ = wf[(kc * 3 + 1) * 64 + l];
        s8v bN = wf[(kc * 3 + 2) * 64 + l];
        accR  = mfma16(a0[kc], bR, accR);
        accZ  = mfma16(a0[kc], bZ, accZ);
        accNi = mfma16(a0[kc], bN, accNi);
    }
    if (has_h) {
        #pragma unroll
        for (int kc = KCX; kc < KC; ++kc) {     // own-layer h(t-1) part
            s8v bR = wf[(kc * 3 + 0) * 64 + l];
            s8v bZ = wf[(kc * 3 + 1) * 64 + l];
            s8v bN = wf[(kc * 3 + 2) * 64 + l];
            accR  = mfma16(a1[kc - KCX], bR, accR);
            accZ  = mfma16(a1[kc - KCX], bZ, accZ);
            accNh = mfma16(a1[kc - KCX], bN, accNh);
        }
    }
}

__global__ __launch_bounds__(256)
void gru_pipe_kernel(const u16* __restrict__ xpack,
                     const u16* __restrict__ Wpk0, const u16* __restrict__ Wpk1,
                     const float* __restrict__ bih0, const float* __restrict__ bhh0,
                     const float* __restrict__ bih1, const float* __restrict__ bhh1,
                     const float* __restrict__ l2W,
                     u16* __restrict__ h0ring, u16* __restrict__ h1ring,
                     int* flags, float* __restrict__ gpartg) {
    __shared__ u16 wlds[16 * 3 * 512];          // 48KB max (L1); L0 uses 36KB
    __shared__ u16 tile[4][16][16];             // per-wave epilogue staging

    const int tid = threadIdx.x;
    const int w = tid >> 6;                     // wave = M-tile (batch group)
    const int l = tid & 63;
    const int q = l >> 4, ncol = l & 15;
    const bool isL1 = blockIdx.x >= 16;
    const int rblk = blockIdx.x & 15;           // 16-channel output slice
    const int KC = isL1 ? 16 : 12;

    int* fL0 = flags;
    int* fL1 = flags + 16;

    // ---- load weight slice into LDS (once) ----
    {
        const s8v* src = (const s8v*)((isL1 ? Wpk1 : Wpk0) + (size_t)rblk * KC * 3 * 512);
        s8v* dst = (s8v*)wlds;
        for (int i = tid; i < KC * 3 * 64; i += 256) dst[i] = src[i];
    }
    // ---- per-lane constants ----
    const int j = rblk * 16 + ncol;
    const float* bihp = isL1 ? bih1 : bih0;
    const float* bhhp = isL1 ? bhh1 : bhh0;
    const float br = bihp[j] + bhhp[j];
    const float bz = bihp[256 + j] + bhhp[256 + j];
    const float bi = bihp[512 + j];
    const float bhn = bhhp[512 + j];
    const float l2v = isL1 ? l2W[j] : 0.0f;
    float hreg[4] = {0.f, 0.f, 0.f, 0.f};
    const int qbase = 2 * (rblk & 1);           // publish q-half for this slice
    u16* myring = isL1 ? h1ring : h0ring;
    const s8v* wf = (const s8v*)wlds;
    __syncthreads();

    for (int t = 0; t < NNODE; ++t) {
        // ---- flag wait (monotone condition; every wave polls independently)
        {
            int tgt0 = isL1 ? t + 1 : t;
            int tgt1 = isL1 ? t : t - 7;
            while (true) {
                int v, tg;
                if (l < 16)      { v = __hip_atomic_load(fL0 + l, __ATOMIC_RELAXED, __HIP_MEMORY_SCOPE_AGENT); tg = tgt0; }
                else if (l < 32) { v = __hip_atomic_load(fL1 + (l - 16), __ATOMIC_RELAXED, __HIP_MEMORY_SCOPE_AGENT); tg = tgt1; }
                else             { v = 0; tg = -0x7fffffff; }
                if (__all(v >= tg)) break;
                __builtin_amdgcn_s_sleep(2);
            }
            asm volatile("" ::: "memory");
        }
        // ---- A-fragment loads ----
        s8v a0[8], a1[8];
        if (isL1) {
            const u64* s0 = (const u64*)(h0ring + (size_t)(t & (RING - 1)) * SLOTU16);
            #pragma unroll
            for (int k = 0; k < 8; ++k) a0[k] = ld_ring(s0 + (size_t)(w * 8 + k) * 128 + l * 2);
            if (t > 0) {
                const u64* s1 = (const u64*)(h1ring + (size_t)((t - 1) & (RING - 1)) * SLOTU16);
                #pragma unroll
                for (int k = 0; k < 8; ++k) a1[k] = ld_ring(s1 + (size_t)(w * 8 + k) * 128 + l * 2);
            }
        } else {
            #pragma unroll
            for (int k = 0; k < 4; ++k)
                a0[k] = *(const s8v*)(xpack + (((size_t)t * 4 + w) * 4 + k) * 512 + (size_t)l * 8);
            if (t > 0) {
                const u64* s1 = (const u64*)(h0ring + (size_t)((t - 1) & (RING - 1)) * SLOTU16);
                #pragma unroll
                for (int k = 0; k < 8; ++k) a1[k] = ld_ring(s1 + (size_t)(w * 8 + k) * 128 + l * 2);
            }
        }
        // ---- MFMA ----
        f4v accR = {0,0,0,0}, accZ = {0,0,0,0}, accNi = {0,0,0,0}, accNh = {0,0,0,0};
        if (isL1) mfma_step<8, 16>(wf, a0, a1, l, t > 0, accR, accZ, accNi, accNh);
        else      mfma_step<4, 12>(wf, a0, a1, l, t > 0, accR, accZ, accNi, accNh);
        // ---- gate epilogue (all gates in-wave; fp32 h in registers) ----
        float pd[4];
        #pragma unroll
        for (int rr = 0; rr < 4; ++rr) {
            float rv = sigm(accR[rr] + br);
            float zv = sigm(accZ[rr] + bz);
            float nv = tanh_(accNi[rr] + bi + rv * (accNh[rr] + bhn));
            float hn = nv + zv * (hreg[rr] - nv);
            hreg[rr] = hn;
            tile[w][q * 4 + rr][ncol] = f2b(hn);
            pd[rr] = hn * l2v;
        }
        if (isL1) {
            #pragma unroll
            for (int rr = 0; rr < 4; ++rr) {
                float v = pd[rr];
                v += __shfl_xor(v, 1); v += __shfl_xor(v, 2);
                v += __shfl_xor(v, 4); v += __shfl_xor(v, 8);
                if (ncol == 0)
                    gpartg[((size_t)t * 16 + rblk) * 64 + w * 16 + q * 4 + rr] = v;
            }
        }
        // ---- publish slice fragment (32 lanes whose q-half matches) ----
        if (q == qbase || q == qbase + 1) {
            s8v v = *(const s8v*)&tile[w][ncol][8 * (q - qbase)];
            u64* dst = (u64*)(myring + (size_t)(t & (RING - 1)) * SLOTU16)
                       + (size_t)(w * 8 + (rblk >> 1)) * 128 + l * 2;
            st_ring(dst, v);
        }
        __syncthreads();   // drains vmcnt (ring stores) + lgkm before flag
        if (tid == 0)
            __hip_atomic_store((isL1 ? fL1 : fL0) + rblk, t + 1,
                               __ATOMIC_RELAXED, __HIP_MEMORY_SCOPE_AGENT);
    }
}

// ------------------------------- final head --------------------------------
__global__ __launch_bounds__(256)
void head_kernel(const float* __restrict__ gpartg, const float* __restrict__ hdot,
                 const float* __restrict__ l1b, const float* __restrict__ l2b,
                 const float* __restrict__ l3W, const float* __restrict__ l3b,
                 float* __restrict__ out) {
    int idx = blockIdx.x * 256 + threadIdx.x;
    if (idx >= NBATCH * NNODE * 12) return;
    int r = idx / 12, oc = idx - r * 12;
    int b = r >> 9, n = r & 511;
    float g = 0.0f;
    #pragma unroll
    for (int k = 0; k < 16; ++k) g += gpartg[((size_t)n * 16 + k) * 64 + b];
    g += l2b[0];
    float hh = hdot[r] + l1b[0];
    out[idx] = g * l3W[oc] + hh * l3W[12 + oc] + l3b[oc];
}

// ------------------------------ host launcher ------------------------------
extern "C" void kernel_launch(void* const* d_in, const int* in_sizes, int n_in,
                              void* d_out, int out_size, void* d_ws, size_t ws_size,
                              hipStream_t stream) {
    const float* x    = (const float*)d_in[0];
    const int*   ei   = (const int*)  d_in[1];
    const float* ew   = (const float*)d_in[2];
    const float* Wz   = (const float*)d_in[3];
    const float* bz   = (const float*)d_in[4];
    const float* lzW  = (const float*)d_in[5];
    const float* lzb  = (const float*)d_in[6];
    // d_in[7..10] (TGCN r-gate) unused: H0 == 0
    const float* Wh   = (const float*)d_in[11];
    const float* bh   = (const float*)d_in[12];
    const float* lhW  = (const float*)d_in[13];
    const float* lhb  = (const float*)d_in[14];
    const float* Wih0 = (const float*)d_in[15];
    const float* Whh0 = (const float*)d_in[16];
    const float* bih0 = (const float*)d_in[17];
    const float* bhh0 = (const float*)d_in[18];
    const float* Wih1 = (const float*)d_in[19];
    const float* Whh1 = (const float*)d_in[20];
    const float* bih1 = (const float*)d_in[21];
    const float* bhh1 = (const float*)d_in[22];
    const float* l1W  = (const float*)d_in[23];
    const float* l1b  = (const float*)d_in[24];
    const float* l2W  = (const float*)d_in[25];
    const float* l2b  = (const float*)d_in[26];
    const float* l3W  = (const float*)d_in[27];
    const float* l3b  = (const float*)d_in[28];

    char* ws = (char*)d_ws;
    size_t o = 0;
    auto take = [&](size_t nbytes) {
        char* p = ws + o;
        o = (o + nbytes + 255) & ~(size_t)255;
        return p;
    };
    float* deg    = (float*)take(NNODE * 4);
    float* dinv   = (float*)take(NNODE * 4);
    int*   rowptr = (int*)  take((NNODE + 1) * 4);
    int*   cursor = (int*)  take(NNODE * 4);
    int*   col    = (int*)  take((NEDGE + NNODE) * 4);
    float* val    = (float*)take((NEDGE + NNODE) * 4);
    u16*   Wf     = (u16*)  take((size_t)512 * DCIN * 2);
    float* bfold  = (float*)take(512 * 4);
    float* hdot   = (float*)take((size_t)NBATCH * NNODE * 4);
    float* gpartg = (float*)take((size_t)NNODE * 16 * 64 * 4);         // 2 MB
    u16*   xpack  = (u16*)  take((size_t)NNODE * 4 * 4 * 512 * 2);     // 8.4 MB
    u16*   Wpk0   = (u16*)  take((size_t)16 * 12 * 3 * 512 * 2);       // 590 KB
    u16*   Wpk1   = (u16*)  take((size_t)16 * 16 * 3 * 512 * 2);       // 786 KB
    u16*   h0ring = (u16*)  take((size_t)RING * SLOTU16 * 2);          // 256 KB
    u16*   h1ring = (u16*)  take((size_t)RING * SLOTU16 * 2);          // 256 KB
    int*   flags  = (int*)  take(256);
    if (o > ws_size) return;   // clean-failure signature: absmax == 4.57e-2

    // preprocessing + repacks (flags MUST be zeroed before gru_pipe)
    init_kernel<<<2, 256, 0, stream>>>(deg, cursor, flags);
    edge_deg_kernel<<<NEDGE / 256, 256, 0, stream>>>(ei, ew, deg, cursor);
    scan_kernel<<<1, NNODE, 0, stream>>>(deg, cursor, dinv, rowptr, cursor, col, val);
    fill_kernel<<<NEDGE / 256, 256, 0, stream>>>(ei, ew, dinv, cursor, col, val);
    fold_kernel<<<512, DCIN, 0, stream>>>(Wz, lzW, bz, lzb, Wh, lhW, bh, lhb, Wf, bfold);
    repack_w_kernel<<<(16 * 12 * 3 * 64 + 255) / 256, 256, 0, stream>>>(
        Wih0, Whh0, 4, 12, DCIN, DHID, Wpk0);
    repack_w_kernel<<<(16 * 16 * 3 * 64 + 255) / 256, 256, 0, stream>>>(
        Wih1, Whh1, 8, 16, DHID, DHID, Wpk1);
    repack_x_kernel<<<(NNODE * 4 * 4 * 64) / 256, 256, 0, stream>>>(x, xpack);

    // fused branches
    tgcn_kernel<<<512, 256, 0, stream>>>(x, rowptr, col, val, Wf, bfold, l1W, hdot);
    gru_pipe_kernel<<<32, 256, 0, stream>>>(xpack, Wpk0, Wpk1, bih0, bhh0,
                                            bih1, bhh1, l2W, h0ring, h1ring,
                                            flags, gpartg);
    head_kernel<<<(NBATCH * NNODE * 12 + 255) / 256, 256, 0, stream>>>(
        gpartg, hdot, l1b, l2b, l3W, l3b, (float*)d_out);
    (void)in_sizes; (void)n_in; (void)out_size;
}